// Round 1
// baseline (218.173 us; speedup 1.0000x reference)
//
#include <hip/hip_runtime.h>

#define N_NODES 100000
#define N_EDGES 1600000
#define IN_F 128
#define OUT_F 32

// ---------------------------------------------------------------------------
// Kernel 1: support = x @ W    [N,128] x [128,32] -> [N,32]
// Block: 256 threads = 8 rows x 32 feature-lanes. W staged in LDS (16 KB),
// 8 x-rows staged in LDS via float4 coalesced loads (4 KB).
// ---------------------------------------------------------------------------
__global__ __launch_bounds__(256) void gcn_gemm(const float* __restrict__ x,
                                                const float* __restrict__ w,
                                                float* __restrict__ support) {
    __shared__ float ws[IN_F][OUT_F];   // 16 KB, w is [128][32] row-major
    __shared__ float xs[8][IN_F];       // 4 KB
    const int tid = threadIdx.x;

    // Load W: 4096 floats, 16 per thread, coalesced.
    #pragma unroll
    for (int i = tid; i < IN_F * OUT_F; i += 256) {
        ws[i >> 5][i & 31] = w[i];
    }

    const int rowBase = blockIdx.x * 8;   // 100000 % 8 == 0, grid covers exactly

    // Load 8 rows of x: 1024 floats = one float4 per thread, coalesced.
    {
        const int idx = tid * 4;          // 0..1023
        const int r = idx >> 7;           // /128
        const int c = idx & 127;
        const float4 v = *reinterpret_cast<const float4*>(&x[(size_t)(rowBase + r) * IN_F + c]);
        *reinterpret_cast<float4*>(&xs[r][c]) = v;
    }
    __syncthreads();

    const int f = tid & 31;    // output feature
    const int r = tid >> 5;    // row within block
    float acc = 0.f;
    #pragma unroll
    for (int k = 0; k < IN_F; ++k) {
        // xs[r][k]: broadcast across the 32 lanes of a row-group (no conflict)
        // ws[k][f]: lanes hit 32 consecutive banks (no conflict)
        acc += xs[r][k] * ws[k][f];
    }
    support[(size_t)(rowBase + r) * OUT_F + f] = acc;
}

// ---------------------------------------------------------------------------
// Kernel 2: out[n][f] = bias[f]   (init before scatter-add)
// ---------------------------------------------------------------------------
__global__ __launch_bounds__(256) void gcn_bias_init(const float* __restrict__ bias,
                                                     float* __restrict__ out) {
    const int i = blockIdx.x * 256 + threadIdx.x;   // over N*32 = 3.2M
    if (i < N_NODES * OUT_F) out[i] = bias[i & 31];
}

// ---------------------------------------------------------------------------
// Kernel 3: for each edge e: out[row[e]][:] += val[e] * support[col[e]][:]
// 32 lanes per edge (one per feature). Gather of support[col] is a coalesced
// 128B segment; atomicAdd targets 32 consecutive floats.
// ---------------------------------------------------------------------------
__global__ __launch_bounds__(256) void gcn_scatter(const int* __restrict__ row,
                                                   const int* __restrict__ col,
                                                   const float* __restrict__ val,
                                                   const float* __restrict__ support,
                                                   float* __restrict__ out) {
    const int f = threadIdx.x & 31;
    const int grp = threadIdx.x >> 5;                      // 0..7 edge-groups/block
    long long e = (long long)blockIdx.x * 8 + grp;
    const long long stride = (long long)gridDim.x * 8;
    for (; e < N_EDGES; e += stride) {
        const int r = row[e];          // same addr across 32 lanes -> broadcast
        const int c = col[e];
        const float v = val[e];
        const float s = support[(size_t)c * OUT_F + f];
        atomicAdd(&out[(size_t)r * OUT_F + f], v * s);
    }
}

extern "C" void kernel_launch(void* const* d_in, const int* in_sizes, int n_in,
                              void* d_out, int out_size, void* d_ws, size_t ws_size,
                              hipStream_t stream) {
    const float* x       = (const float*)d_in[0];
    const int*   adj_row = (const int*)d_in[1];
    const int*   adj_col = (const int*)d_in[2];
    const float* adj_val = (const float*)d_in[3];
    const float* weight  = (const float*)d_in[4];
    const float* bias    = (const float*)d_in[5];
    float* out = (float*)d_out;

    float* support = (float*)d_ws;   // N_NODES * OUT_F * 4 = 12.8 MB

    // 1) support = x @ W
    gcn_gemm<<<N_NODES / 8, 256, 0, stream>>>(x, weight, support);

    // 2) out = bias (broadcast)
    gcn_bias_init<<<(N_NODES * OUT_F + 255) / 256, 256, 0, stream>>>(bias, out);

    // 3) scatter-add over edges
    gcn_scatter<<<8192, 256, 0, stream>>>(adj_row, adj_col, adj_val, support, out);
}